// Round 8
// baseline (167.936 us; speedup 1.0000x reference)
//
#include <hip/hip_runtime.h>

typedef unsigned short u16;
typedef __attribute__((ext_vector_type(8))) short short8;
typedef __attribute__((ext_vector_type(4))) short short4v;
typedef __attribute__((ext_vector_type(4))) float f32x4;
typedef __attribute__((ext_vector_type(4))) float float4v;
typedef __attribute__((ext_vector_type(4))) unsigned short u16x4;

#define AS1 __attribute__((address_space(1)))
#define AS3 __attribute__((address_space(3)))

// B=2, T=2048, C=1024, H=16, HD=64
#define Tn 2048
#define Cn 1024
#define Hn 16
#define HDn 64

#if __has_builtin(__builtin_amdgcn_exp2f)
#define EXP2(x) __builtin_amdgcn_exp2f(x)   // bare v_exp_f32 (no ocml denorm fixup)
#else
#define EXP2(x) exp2f(x)
#endif

struct FalseT { static constexpr bool value = false; };
struct TrueT  { static constexpr bool value = true;  };

static __device__ __forceinline__ u16 f2bf(float f) {
    unsigned int u = __float_as_uint(f);
    u += 0x7FFFu + ((u >> 16) & 1u);   // round-to-nearest-even
    return (u16)(u >> 16);
}

static __device__ __forceinline__ void ldlds16(const void* g, void* l) {
    __builtin_amdgcn_global_load_lds((const AS1 unsigned int*)g,
                                     (AS3 unsigned int*)l, 16, 0, 0);
}

// ---------------- fused prep: x->bf16 | Wqkv^T->bf16 | Wo^T->bf16 ----------------
__global__ void prep(const float* __restrict__ x, u16* __restrict__ xb,
                     const float* __restrict__ Wqkv, u16* __restrict__ wqkvt,
                     const float* __restrict__ Wo, u16* __restrict__ wot) {
    __shared__ float t[64][65];
    const int bx = blockIdx.x, tid = threadIdx.x;
    if (bx < 4096) {
        int i = bx * 256 + tid;
        float4v v = ((const float4v*)x)[i];
        u16x4 o;
        o.x = f2bf(v.x); o.y = f2bf(v.y); o.z = f2bf(v.z); o.w = f2bf(v.w);
        ((u16x4*)xb)[i] = o;
        return;
    }
    const float* in; u16* out; int R, Cc, r0, c0;
    if (bx < 4864) {
        int idx = bx - 4096;
        in = Wqkv; out = wqkvt; R = 1024; Cc = 3072;
        c0 = (idx % 48) * 64; r0 = (idx / 48) * 64;
    } else {
        int idx = bx - 4864;
        in = Wo; out = wot; R = 1024; Cc = 1024;
        c0 = (idx & 15) * 64; r0 = (idx >> 4) * 64;
    }
    int tx = tid & 63, ty = tid >> 6;
#pragma unroll
    for (int i = 0; i < 64; i += 4)
        t[ty + i][tx] = in[(long)(r0 + ty + i) * Cc + c0 + tx];
    __syncthreads();
#pragma unroll
    for (int i = 0; i < 64; i += 4)
        out[(long)(c0 + ty + i) * R + r0 + tx] = f2bf(t[tx][ty + i]);
}

// ---------------- m97-style GEMM, BK=64 (unchanged from R7, proven) ----------------
template <int MODE>
__global__ __launch_bounds__(256, 3)
void gemm_bt(const u16* __restrict__ A, const u16* __restrict__ Bt,
             const float* __restrict__ bias,
             u16* __restrict__ o16, u16* __restrict__ vout,
             float* __restrict__ f_out,
             int M, int N, int K) {
    __shared__ __attribute__((aligned(16))) u16 As[128 * 64];
    __shared__ __attribute__((aligned(16))) u16 Bs[128 * 64];
    const int tid = threadIdx.x;
    const int l = tid & 63;
    const int w = tid >> 6;
    const int wm = (w >> 1) * 64, wn = (w & 1) * 64;
    const long m0 = (long)blockIdx.x * 128, n0 = (long)blockIdx.y * 128;
    const int lm = l & 15, g = l >> 4;

    const int sr = tid >> 3;                         // 0..31 (row base, j adds 32)
    const int scx = (tid & 7) ^ ((tid >> 3) & 7);    // pre-swizzled col segment
    const u16* Ag = A + (m0 + sr) * K + scx * 8;
    const u16* Bg = Bt + (n0 + sr) * K + scx * 8;
    u16* Asl = As + tid * 8;
    u16* Bsl = Bs + tid * 8;
    const int xr = lm & 7;                           // read-side row XOR

    f32x4 acc[4][4] = {};

    for (int k0 = 0; k0 < K; k0 += 64) {
        __syncthreads();
#pragma unroll
        for (int j = 0; j < 4; ++j) {
            ldlds16(Ag + k0 + (long)(j * 32) * K, Asl + j * 2048);
            ldlds16(Bg + k0 + (long)(j * 32) * K, Bsl + j * 2048);
        }
        __syncthreads();
#pragma unroll
        for (int kk = 0; kk < 2; ++kk) {
            const int cs0 = ((kk * 4 + g) ^ xr) * 8;
            short8 af[4], bf[4];
#pragma unroll
            for (int mt = 0; mt < 4; ++mt)
                af[mt] = *(const short8*)(As + (wm + mt * 16 + lm) * 64 + cs0);
#pragma unroll
            for (int nt = 0; nt < 4; ++nt)
                bf[nt] = *(const short8*)(Bs + (wn + nt * 16 + lm) * 64 + cs0);
#pragma unroll
            for (int mt = 0; mt < 4; ++mt)
#pragma unroll
                for (int nt = 0; nt < 4; ++nt)
                    acc[mt][nt] = __builtin_amdgcn_mfma_f32_16x16x32_bf16(
                        af[mt], bf[nt], acc[mt][nt], 0, 0, 0);
        }
    }

    if (MODE == 0 && n0 >= 2048) {
        // ---- fused V^T emit: transpose 128x128 tile via LDS (As), 2 passes ----
        const long b = m0 >> 11;
        const int t0 = (int)(m0 & 2047);
        const int n0b = (int)(n0 - 2048);
#pragma unroll
        for (int p = 0; p < 2; ++p) {
            __syncthreads();               // prior LDS reads (k-loop / pass p-1) done
            if ((w & 1) == p) {            // waves whose wn == p*64 hold this n-half
#pragma unroll
                for (int mt = 0; mt < 4; ++mt) {
                    const int colu = wm + mt * 16 + g * 4;   // m_local base (4-aligned)
#pragma unroll
                    for (int nt = 0; nt < 4; ++nt) {
                        const int row = nt * 16 + lm;        // n_local in 0..63
                        float bv = bias[n0 + p * 64 + row];
                        u16 tmp[4];
#pragma unroll
                        for (int r = 0; r < 4; ++r)
                            tmp[r] = f2bf(acc[mt][nt][r] + bv);
                        // XOR-swizzle columns by row to avoid 16-way write conflicts
                        *(u16x4*)(As + row * 128 + (colu ^ (lm << 3))) = *(const u16x4*)tmp;
                    }
                }
            }
            __syncthreads();
            {   // coalesced V^T store: 4 threads per n-row, 64B each along t
                const int nl = tid >> 2, mb = (tid & 3) * 32;
                const int ng = n0b + p * 64 + nl;
                u16* dst = vout + (((b * 16 + (ng >> 6)) * 64 + (ng & 63)) * (long)Tn) + t0;
#pragma unroll
                for (int j = 0; j < 4; ++j) {
                    const int c = mb + j * 8;
                    *(short8*)(dst + c) =
                        *(const short8*)(As + nl * 128 + (c ^ ((nl & 15) << 3)));
                }
            }
        }
        return;
    }

    const int r0 = (l >> 4) * 4;
#pragma unroll
    for (int mt = 0; mt < 4; ++mt) {
#pragma unroll
        for (int nt = 0; nt < 4; ++nt) {
            long n = n0 + wn + nt * 16 + lm;
            float bv = bias[n];
            // fold softmax scale (0.125*log2e) into Q columns at MODE 0
            float scq = (MODE == 0 && n < 1024) ? 0.18033688f : 1.0f;
#pragma unroll
            for (int r = 0; r < 4; ++r) {
                long m = m0 + wm + mt * 16 + r0 + r;
                float v = (acc[mt][nt][r] + bv) * scq;
                if (MODE == 0) o16[m * N + n] = f2bf(v);
                else           f_out[m * N + n] = v;
            }
        }
    }
}

// ---------------- 64x128-tile fp32-out GEMM (Wo projection), 512-thread, BK=64 ----
// Same BK=64 transformation proven on gemm_bt in R7: 16 MFMA per barrier pair
// (was 4 at BK=32), staging via pre-swizzled global col + linear LDS dest +
// read-side XOR (both-sides involution). 24KB LDS, (512,2) -> 16 waves/CU.
__global__ __launch_bounds__(512, 2)
void gemm_bt64(const u16* __restrict__ A, const u16* __restrict__ Bt,
               const float* __restrict__ bias, float* __restrict__ f_out,
               int M, int N, int K) {
    __shared__ __attribute__((aligned(16))) u16 As[64 * 64];
    __shared__ __attribute__((aligned(16))) u16 Bs[128 * 64];
    const int tid = threadIdx.x;          // 0..511
    const int l = tid & 63;
    const int w = tid >> 6;               // 0..7
    const int wm = (w & 1) * 32, wn = (w >> 1) * 32;
    const long m0 = (long)blockIdx.x * 64, n0 = (long)blockIdx.y * 128;
    const int lm = l & 15, g = l >> 4;

    const int sr = tid >> 3;                         // 0..63
    const int scx = (tid & 7) ^ ((tid >> 3) & 7);    // pre-swizzled col segment
    const u16* Ag = A + (m0 + sr) * K + scx * 8;
    const u16* Bg = Bt + (n0 + sr) * K + scx * 8;    // row +64 adds 64*K, same swz (&7)
    u16* Asl = As + tid * 8;
    u16* Bsl = Bs + tid * 8;
    const int xr = lm & 7;

    f32x4 acc[2][2] = {};

    for (int k0 = 0; k0 < K; k0 += 64) {
        __syncthreads();
        ldlds16(Ag + k0, Asl);
        ldlds16(Bg + k0, Bsl);
        ldlds16(Bg + k0 + (long)64 * K, Bsl + 4096);
        __syncthreads();
#pragma unroll
        for (int kk = 0; kk < 2; ++kk) {
            const int cs0 = ((kk * 4 + g) ^ xr) * 8;
            short8 af[2], bf[2];
#pragma unroll
            for (int mt = 0; mt < 2; ++mt)
                af[mt] = *(const short8*)(As + (wm + mt * 16 + lm) * 64 + cs0);
#pragma unroll
            for (int nt = 0; nt < 2; ++nt)
                bf[nt] = *(const short8*)(Bs + (wn + nt * 16 + lm) * 64 + cs0);
#pragma unroll
            for (int mt = 0; mt < 2; ++mt)
#pragma unroll
                for (int nt = 0; nt < 2; ++nt)
                    acc[mt][nt] = __builtin_amdgcn_mfma_f32_16x16x32_bf16(
                        af[mt], bf[nt], acc[mt][nt], 0, 0, 0);
        }
    }

    const int r0 = g * 4;
#pragma unroll
    for (int mt = 0; mt < 2; ++mt) {
#pragma unroll
        for (int nt = 0; nt < 2; ++nt) {
            long n = n0 + wn + nt * 16 + lm;
            float bv = bias[n];
#pragma unroll
            for (int r = 0; r < 4; ++r) {
                long m = m0 + wm + mt * 16 + r0 + r;
                f_out[m * N + n] = acc[mt][nt][r] + bv;
            }
        }
    }
}

// ---------------- flash attention: fused-job S^T formulation ----------------
// R7 wave geometry (proven): 512 threads = 8 waves, 4-way q-split (mh) x 2-way
// s-split (sh); XCD-aware bijective block swizzle; bare-EXP2 softmax.
// NEW: job fusion. qt_b=px's K/V tiles are a strict subset of qt_a=31-px's, so
// stage each tile ONCE and run both bodies per barrier window (body_b while
// i<n_b). Barrier pairs/block: n_a+n_b (~17) -> n_a (9..16); staging -26%; the
// two bodies are register-independent -> ILP across MFMA/VALU phases. Body count
// stays 17/block for every px (load-balanced). Per-job state duplicated
// (o_acc/qa/lsum, ~+30 VGPR) -> launch_bounds(512,2) = 128-VGPR cap; occupancy
// unchanged (LDS-bound at 2 blocks/CU).
// LDS 64 KB: Ks[2] 128x64 @0/8192, Vs[2] 64x128 @16384/24576 (u16 idx).
__global__ __launch_bounds__(512, 2)
void attn(const u16* __restrict__ qkv, const u16* __restrict__ Vt,
          u16* __restrict__ Y) {
    __shared__ __attribute__((aligned(16))) u16 S_lds[32768];

    // XCD swizzle: lin = hw linear block id; residue class (lin&7) -> 64 blocks
    // = bh in [4c, 4c+4) x px 0..15, all co-resident on one XCD.
    const int lin = blockIdx.x + (blockIdx.y << 4);
    const int s = (lin & 7) * 64 + (lin >> 3);
    const int px = s & 15;                 // 0..15
    const int bh = s >> 4;                 // 0..31
    const int tid = threadIdx.x, l = tid & 63, w = tid >> 6;   // w 0..7
    const int mh = w >> 1, sh = w & 1;
    const int lm = l & 15, g = l >> 4;
    const int lm7 = lm & 7;
    const int mh16 = mh * 16, sh64 = sh * 64, sh8 = sh * 8, g4 = g * 4;
    const int b = bh >> 4, h = bh & 15;

    const u16* Kp = qkv + (long)b * Tn * 3072 + 1024 + h * 64;
    const u16* Vp = Vt + (long)bh * HDn * Tn;

    // 512-thread staging: K 64 rows/round (2 rounds), V 32 rows/round (2 rounds)
    const int soffK = (tid >> 3) * 3072 + (((tid & 7) ^ ((tid >> 3) & 7)) * 8);
    const int soffV = (tid >> 4) * Tn + (((tid & 15) ^ ((tid >> 4) & 15)) * 8);

    auto prefetch = [&](int i, int buf) {
        u16* Kn = S_lds + buf * 8192;
        u16* Vn = S_lds + 16384 + buf * 8192;
        const u16* Kt = Kp + (long)i * 128 * 3072;
        const u16* Vg = Vp + i * 128;
#pragma unroll
        for (int j = 0; j < 2; ++j) {
            ldlds16(Kt + j * (64 * 3072) + soffK, Kn + j * 4096 + tid * 8);
            ldlds16(Vg + j * (32 * Tn) + soffV, Vn + j * 4096 + tid * 8);
        }
    };

    const int qtA = 31 - px, qtB = px;
    const int nA = (qtA >> 1) + 1;        // 9..16
    const int nB = (qtB >> 1) + 1;        // 1..8  (nB < nA always)
    const int qrowA = qtA * 64 + mh16 + lm;
    const int qrowB = qtB * 64 + mh16 + lm;

    // Q fragments (B-operand of S^T mfma): Q[q=mh16+lm][d=hh*32+g*8+j]
    const u16* QpA = qkv + ((long)b * Tn + qtA * 64) * 3072 + h * 64;
    const u16* QpB = qkv + ((long)b * Tn + qtB * 64) * 3072 + h * 64;
    short8 qaA[2], qaB[2];
#pragma unroll
    for (int hh = 0; hh < 2; ++hh) {
        qaA[hh] = *(const short8*)(QpA + (mh16 + lm) * 3072 + hh * 32 + g * 8);
        qaB[hh] = *(const short8*)(QpB + (mh16 + lm) * 3072 + hh * 32 + g * 8);
    }

    f32x4 o_accA[4] = {}, o_accB[4] = {};   // O^T[d=dt*16+g4+r][q=mh16+lm]
    float lsumA = 0.f, lsumB = 0.f;

    auto body = [&](int buf, int sbase, short8 (&qa)[2], f32x4 (&o_acc)[4],
                    float& lsum, int qrow, auto diag_c) {
        constexpr bool DIAG = decltype(diag_c)::value;
        const u16* Kc = S_lds + buf * 8192;
        const u16* Vc = S_lds + 16384 + buf * 8192;
        // S^T = K * Q^T : 1 q-tile x 4 s-tiles, k=64
        f32x4 st[4];
#pragma unroll
        for (int nt = 0; nt < 4; ++nt)
            st[nt] = (f32x4){0.f, 0.f, 0.f, 0.f};
#pragma unroll
        for (int nt = 0; nt < 4; ++nt)
#pragma unroll
            for (int hh = 0; hh < 2; ++hh) {
                short8 kf = *(const short8*)(Kc + (sh64 + nt * 16 + lm) * 64 +
                                             (((hh * 4 + g) ^ lm7) * 8));
                st[nt] = __builtin_amdgcn_mfma_f32_16x16x32_bf16(kf, qa[hh], st[nt], 0, 0, 0);
            }
        // exp2 + mask + pack to bf16 B-fragments (P^T stays in registers)
        short4v pb[4];
#pragma unroll
        for (int nt = 0; nt < 4; ++nt) {
            const int scolb = sbase + sh64 + nt * 16 + g4;
#pragma unroll
            for (int r = 0; r < 4; ++r) {
                float xx = st[nt][r];
                if (DIAG && scolb + r > qrow) xx = -1e30f;
                float p = EXP2(xx);
                lsum += p;
                pb[nt][r] = (short)(__float_as_uint(p) >> 16);
            }
        }
        // O^T += V^T * P^T : per (s-16-chunk, d-tile) one 16x16x16 MFMA
#pragma unroll
        for (int nt = 0; nt < 4; ++nt) {
            const int vcol = (((sh8 + nt * 2 + (g >> 1)) ^ lm) * 8) + (g & 1) * 4;
#pragma unroll
            for (int dt = 0; dt < 4; ++dt) {
                short4v vf = *(const short4v*)(Vc + (dt * 16 + lm) * 128 + vcol);
                o_acc[dt] = __builtin_amdgcn_mfma_f32_16x16x16bf16_1k(vf, pb[nt], o_acc[dt], 0, 0, 0);
            }
        }
    };

    prefetch(0, 0);
    __syncthreads();
    for (int i = 0; i < nA; ++i) {
        const int buf = i & 1;
        if (i + 1 < nA) prefetch(i + 1, buf ^ 1);
        const int sbase = i * 128;
        if (i == nA - 1) body(buf, sbase, qaA, o_accA, lsumA, qrowA, TrueT{});
        else             body(buf, sbase, qaA, o_accA, lsumA, qrowA, FalseT{});
        if (i < nB) {
            if (i == nB - 1) body(buf, sbase, qaB, o_accB, lsumB, qrowB, TrueT{});
            else             body(buf, sbase, qaB, o_accB, lsumB, qrowB, FalseT{});
        }
        __syncthreads();
    }

    // ---- epilogue per job: cross-sh reduce + transpose via padded f32 LDS ----
    auto epilogue = [&](int qt, f32x4 (&o_acc)[4], float lsum) {
        lsum += __shfl_xor(lsum, 16, 64);
        lsum += __shfl_xor(lsum, 32, 64);
        float* Ytf = (float*)S_lds;               // [64][68] f32 (17408 B)
        float* redl = (float*)(S_lds + 8704);     // 64 f32 @byte 17408

        if (sh == 1) {
            const int q = mh16 + lm;
#pragma unroll
            for (int dt = 0; dt < 4; ++dt)
                *(f32x4*)(Ytf + q * 68 + dt * 16 + g4) = o_acc[dt];
            if (g == 0) redl[q] = lsum;
        }
        __syncthreads();
        if (sh == 0) {
            const int q = mh16 + lm;
            float inv = 1.0f / (lsum + redl[q]);
#pragma unroll
            for (int dt = 0; dt < 4; ++dt) {
                f32x4 t = *(const f32x4*)(Ytf + q * 68 + dt * 16 + g4);
                t += o_acc[dt];
                t *= inv;
                *(f32x4*)(Ytf + q * 68 + dt * 16 + g4) = t;
            }
        }
        __syncthreads();
        {   // coalesced store: 8 threads per q-row, 8 bf16 each
            const int q = tid >> 3, dseg = (tid & 7) * 8;
            long base = ((long)b * Tn + qt * 64 + q) * Cn + h * HDn + dseg;
            u16 tmp[8];
#pragma unroll
            for (int j = 0; j < 8; ++j)
                tmp[j] = f2bf(Ytf[q * 68 + dseg + j]);
            *(short8*)(Y + base) = *(const short8*)tmp;
        }
        __syncthreads();   // Ytf reads done before next epilogue overwrites
    };

    epilogue(qtA, o_accA, lsumA);
    epilogue(qtB, o_accB, lsumB);
}

extern "C" void kernel_launch(void* const* d_in, const int* in_sizes, int n_in,
                              void* d_out, int out_size, void* d_ws, size_t ws_size,
                              hipStream_t stream) {
    const float* x    = (const float*)d_in[0];
    const float* Wqkv = (const float*)d_in[1];
    const float* bqkv = (const float*)d_in[2];
    const float* Wo   = (const float*)d_in[3];
    const float* bo   = (const float*)d_in[4];
    float* out = (float*)d_out;

    u16* xb    = (u16*)d_ws;          // 4M u16 : x bf16
    u16* wqkvt = xb + 4194304;        // 3M : Wqkv^T
    u16* wot   = wqkvt + 3145728;     // 1M : Wo^T
    u16* qkvb  = wot + 1048576;       // 12M : qkv [b,t,3C] bf16 (Q pre-scaled; V third unused)
    u16* vtb   = qkvb + 12582912;     // 4M : V^T [b,h,d,t] (written by gemm_bt<0>)
    u16* yb    = vtb + 4194304;       // 4M : attn out [b,t,c]

    prep<<<5120, 256, 0, stream>>>(x, xb, Wqkv, wqkvt, Wo, wot);
    gemm_bt<0><<<dim3(32, 24), 256, 0, stream>>>(xb, wqkvt, bqkv, qkvb, vtb,
                                                 nullptr, 4096, 3072, 1024);
    attn<<<dim3(16, 32), 512, 0, stream>>>(qkvb, vtb, yb);
    gemm_bt64<<<dim3(64, 8), 512, 0, stream>>>(yb, wot, bo, out, 4096, 1024, 1024);
}

// Round 9
// 164.685 us; speedup vs baseline: 1.0197x; 1.0197x over previous
//
#include <hip/hip_runtime.h>

typedef unsigned short u16;
typedef __attribute__((ext_vector_type(8))) short short8;
typedef __attribute__((ext_vector_type(4))) short short4v;
typedef __attribute__((ext_vector_type(4))) float f32x4;
typedef __attribute__((ext_vector_type(4))) float float4v;
typedef __attribute__((ext_vector_type(4))) unsigned short u16x4;

#define AS1 __attribute__((address_space(1)))
#define AS3 __attribute__((address_space(3)))

// B=2, T=2048, C=1024, H=16, HD=64
#define Tn 2048
#define Cn 1024
#define Hn 16
#define HDn 64

#if __has_builtin(__builtin_amdgcn_exp2f)
#define EXP2(x) __builtin_amdgcn_exp2f(x)   // bare v_exp_f32 (no ocml denorm fixup)
#else
#define EXP2(x) exp2f(x)
#endif

struct FalseT { static constexpr bool value = false; };
struct TrueT  { static constexpr bool value = true;  };

static __device__ __forceinline__ u16 f2bf(float f) {
    unsigned int u = __float_as_uint(f);
    u += 0x7FFFu + ((u >> 16) & 1u);   // round-to-nearest-even
    return (u16)(u >> 16);
}

static __device__ __forceinline__ void ldlds16(const void* g, void* l) {
    __builtin_amdgcn_global_load_lds((const AS1 unsigned int*)g,
                                     (AS3 unsigned int*)l, 16, 0, 0);
}

// ---------------- fused prep: x->bf16 | Wqkv^T->bf16 | Wo^T->bf16 ----------------
__global__ void prep(const float* __restrict__ x, u16* __restrict__ xb,
                     const float* __restrict__ Wqkv, u16* __restrict__ wqkvt,
                     const float* __restrict__ Wo, u16* __restrict__ wot) {
    __shared__ float t[64][65];
    const int bx = blockIdx.x, tid = threadIdx.x;
    if (bx < 4096) {
        int i = bx * 256 + tid;
        float4v v = ((const float4v*)x)[i];
        u16x4 o;
        o.x = f2bf(v.x); o.y = f2bf(v.y); o.z = f2bf(v.z); o.w = f2bf(v.w);
        ((u16x4*)xb)[i] = o;
        return;
    }
    const float* in; u16* out; int R, Cc, r0, c0;
    if (bx < 4864) {
        int idx = bx - 4096;
        in = Wqkv; out = wqkvt; R = 1024; Cc = 3072;
        c0 = (idx % 48) * 64; r0 = (idx / 48) * 64;
    } else {
        int idx = bx - 4864;
        in = Wo; out = wot; R = 1024; Cc = 1024;
        c0 = (idx & 15) * 64; r0 = (idx >> 4) * 64;
    }
    int tx = tid & 63, ty = tid >> 6;
#pragma unroll
    for (int i = 0; i < 64; i += 4)
        t[ty + i][tx] = in[(long)(r0 + ty + i) * Cc + c0 + tx];
    __syncthreads();
#pragma unroll
    for (int i = 0; i < 64; i += 4)
        out[(long)(c0 + ty + i) * R + r0 + tx] = f2bf(t[tx][ty + i]);
}

// ---------------- m97-style GEMM, BK=64 (unchanged from R7, proven) ----------------
template <int MODE>
__global__ __launch_bounds__(256, 3)
void gemm_bt(const u16* __restrict__ A, const u16* __restrict__ Bt,
             const float* __restrict__ bias,
             u16* __restrict__ o16, u16* __restrict__ vout,
             float* __restrict__ f_out,
             int M, int N, int K) {
    __shared__ __attribute__((aligned(16))) u16 As[128 * 64];
    __shared__ __attribute__((aligned(16))) u16 Bs[128 * 64];
    const int tid = threadIdx.x;
    const int l = tid & 63;
    const int w = tid >> 6;
    const int wm = (w >> 1) * 64, wn = (w & 1) * 64;
    const long m0 = (long)blockIdx.x * 128, n0 = (long)blockIdx.y * 128;
    const int lm = l & 15, g = l >> 4;

    const int sr = tid >> 3;                         // 0..31 (row base, j adds 32)
    const int scx = (tid & 7) ^ ((tid >> 3) & 7);    // pre-swizzled col segment
    const u16* Ag = A + (m0 + sr) * K + scx * 8;
    const u16* Bg = Bt + (n0 + sr) * K + scx * 8;
    u16* Asl = As + tid * 8;
    u16* Bsl = Bs + tid * 8;
    const int xr = lm & 7;                           // read-side row XOR

    f32x4 acc[4][4] = {};

    for (int k0 = 0; k0 < K; k0 += 64) {
        __syncthreads();
#pragma unroll
        for (int j = 0; j < 4; ++j) {
            ldlds16(Ag + k0 + (long)(j * 32) * K, Asl + j * 2048);
            ldlds16(Bg + k0 + (long)(j * 32) * K, Bsl + j * 2048);
        }
        __syncthreads();
#pragma unroll
        for (int kk = 0; kk < 2; ++kk) {
            const int cs0 = ((kk * 4 + g) ^ xr) * 8;
            short8 af[4], bf[4];
#pragma unroll
            for (int mt = 0; mt < 4; ++mt)
                af[mt] = *(const short8*)(As + (wm + mt * 16 + lm) * 64 + cs0);
#pragma unroll
            for (int nt = 0; nt < 4; ++nt)
                bf[nt] = *(const short8*)(Bs + (wn + nt * 16 + lm) * 64 + cs0);
#pragma unroll
            for (int mt = 0; mt < 4; ++mt)
#pragma unroll
                for (int nt = 0; nt < 4; ++nt)
                    acc[mt][nt] = __builtin_amdgcn_mfma_f32_16x16x32_bf16(
                        af[mt], bf[nt], acc[mt][nt], 0, 0, 0);
        }
    }

    if (MODE == 0 && n0 >= 2048) {
        // ---- fused V^T emit: transpose 128x128 tile via LDS (As), 2 passes ----
        const long b = m0 >> 11;
        const int t0 = (int)(m0 & 2047);
        const int n0b = (int)(n0 - 2048);
#pragma unroll
        for (int p = 0; p < 2; ++p) {
            __syncthreads();               // prior LDS reads (k-loop / pass p-1) done
            if ((w & 1) == p) {            // waves whose wn == p*64 hold this n-half
#pragma unroll
                for (int mt = 0; mt < 4; ++mt) {
                    const int colu = wm + mt * 16 + g * 4;   // m_local base (4-aligned)
#pragma unroll
                    for (int nt = 0; nt < 4; ++nt) {
                        const int row = nt * 16 + lm;        // n_local in 0..63
                        float bv = bias[n0 + p * 64 + row];
                        u16 tmp[4];
#pragma unroll
                        for (int r = 0; r < 4; ++r)
                            tmp[r] = f2bf(acc[mt][nt][r] + bv);
                        // XOR-swizzle columns by row to avoid 16-way write conflicts
                        *(u16x4*)(As + row * 128 + (colu ^ (lm << 3))) = *(const u16x4*)tmp;
                    }
                }
            }
            __syncthreads();
            {   // coalesced V^T store: 4 threads per n-row, 64B each along t
                const int nl = tid >> 2, mb = (tid & 3) * 32;
                const int ng = n0b + p * 64 + nl;
                u16* dst = vout + (((b * 16 + (ng >> 6)) * 64 + (ng & 63)) * (long)Tn) + t0;
#pragma unroll
                for (int j = 0; j < 4; ++j) {
                    const int c = mb + j * 8;
                    *(short8*)(dst + c) =
                        *(const short8*)(As + nl * 128 + (c ^ ((nl & 15) << 3)));
                }
            }
        }
        return;
    }

    const int r0 = (l >> 4) * 4;
#pragma unroll
    for (int mt = 0; mt < 4; ++mt) {
#pragma unroll
        for (int nt = 0; nt < 4; ++nt) {
            long n = n0 + wn + nt * 16 + lm;
            float bv = bias[n];
            // fold softmax scale (0.125*log2e) into Q columns at MODE 0
            float scq = (MODE == 0 && n < 1024) ? 0.18033688f : 1.0f;
#pragma unroll
            for (int r = 0; r < 4; ++r) {
                long m = m0 + wm + mt * 16 + r0 + r;
                float v = (acc[mt][nt][r] + bv) * scq;
                if (MODE == 0) o16[m * N + n] = f2bf(v);
                else           f_out[m * N + n] = v;
            }
        }
    }
}

// ---------------- 64x128-tile fp32-out GEMM (Wo projection), 512-thread, BK=64 ----
// (kept from R8 -- attribution: mirrors the gemm0 BK=64 win from R7)
__global__ __launch_bounds__(512, 2)
void gemm_bt64(const u16* __restrict__ A, const u16* __restrict__ Bt,
               const float* __restrict__ bias, float* __restrict__ f_out,
               int M, int N, int K) {
    __shared__ __attribute__((aligned(16))) u16 As[64 * 64];
    __shared__ __attribute__((aligned(16))) u16 Bs[128 * 64];
    const int tid = threadIdx.x;          // 0..511
    const int l = tid & 63;
    const int w = tid >> 6;               // 0..7
    const int wm = (w & 1) * 32, wn = (w >> 1) * 32;
    const long m0 = (long)blockIdx.x * 64, n0 = (long)blockIdx.y * 128;
    const int lm = l & 15, g = l >> 4;

    const int sr = tid >> 3;                         // 0..63
    const int scx = (tid & 7) ^ ((tid >> 3) & 7);    // pre-swizzled col segment
    const u16* Ag = A + (m0 + sr) * K + scx * 8;
    const u16* Bg = Bt + (n0 + sr) * K + scx * 8;    // row +64 adds 64*K, same swz (&7)
    u16* Asl = As + tid * 8;
    u16* Bsl = Bs + tid * 8;
    const int xr = lm & 7;

    f32x4 acc[2][2] = {};

    for (int k0 = 0; k0 < K; k0 += 64) {
        __syncthreads();
        ldlds16(Ag + k0, Asl);
        ldlds16(Bg + k0, Bsl);
        ldlds16(Bg + k0 + (long)64 * K, Bsl + 4096);
        __syncthreads();
#pragma unroll
        for (int kk = 0; kk < 2; ++kk) {
            const int cs0 = ((kk * 4 + g) ^ xr) * 8;
            short8 af[2], bf[2];
#pragma unroll
            for (int mt = 0; mt < 2; ++mt)
                af[mt] = *(const short8*)(As + (wm + mt * 16 + lm) * 64 + cs0);
#pragma unroll
            for (int nt = 0; nt < 2; ++nt)
                bf[nt] = *(const short8*)(Bs + (wn + nt * 16 + lm) * 64 + cs0);
#pragma unroll
            for (int mt = 0; mt < 2; ++mt)
#pragma unroll
                for (int nt = 0; nt < 2; ++nt)
                    acc[mt][nt] = __builtin_amdgcn_mfma_f32_16x16x32_bf16(
                        af[mt], bf[nt], acc[mt][nt], 0, 0, 0);
        }
    }

    const int r0 = g * 4;
#pragma unroll
    for (int mt = 0; mt < 2; ++mt) {
#pragma unroll
        for (int nt = 0; nt < 2; ++nt) {
            long n = n0 + wn + nt * 16 + lm;
            float bv = bias[n];
#pragma unroll
            for (int r = 0; r < 4; ++r) {
                long m = m0 + wm + mt * 16 + r0 + r;
                f_out[m * N + n] = acc[mt][nt][r] + bv;
            }
        }
    }
}

// ---------------- flash attention: S^T formulation, zero P round-trip ----------------
// R7-exact version (best measured: ~41us). 512 threads = 8 waves, 4-way q-split
// (mh) x 2-way s-split (sh); XCD-aware bijective block swizzle (FETCH 91->12MB);
// bare-EXP2 softmax. R8's job-fusion (shared K/V staging for both qt jobs)
// REGRESSED ~3us: doubled serial VALU chain per barrier window + ~+30 VGPR ate
// the expected ILP -- attn is dependency-bound, not staging-bound. Reverted.
// Q pre-scaled by 0.125*log2e in gemm_bt<0>, so softmax inner loop is bare exp2.
// LDS 64 KB: Ks[2] 128x64 @0/8192, Vs[2] 64x128 @16384/24576 (u16 idx).
__global__ __launch_bounds__(512, 4)
void attn(const u16* __restrict__ qkv, const u16* __restrict__ Vt,
          u16* __restrict__ Y) {
    __shared__ __attribute__((aligned(16))) u16 S_lds[32768];

    // XCD swizzle: lin = hw linear block id; residue class (lin&7) -> 64 blocks
    // = bh in [4c, 4c+4) x px 0..15, all co-resident on one XCD.
    const int lin = blockIdx.x + (blockIdx.y << 4);
    const int s = (lin & 7) * 64 + (lin >> 3);
    const int px = s & 15;                 // 0..15
    const int bh = s >> 4;                 // 0..31
    const int tid = threadIdx.x, l = tid & 63, w = tid >> 6;   // w 0..7
    const int mh = w >> 1, sh = w & 1;
    const int lm = l & 15, g = l >> 4;
    const int lm7 = lm & 7;
    const int mh16 = mh * 16, sh64 = sh * 64, sh8 = sh * 8, g4 = g * 4;
    const int b = bh >> 4, h = bh & 15;

    const u16* Kp = qkv + (long)b * Tn * 3072 + 1024 + h * 64;
    const u16* Vp = Vt + (long)bh * HDn * Tn;

    // 512-thread staging: K 64 rows/round (2 rounds), V 32 rows/round (2 rounds)
    const int soffK = (tid >> 3) * 3072 + (((tid & 7) ^ ((tid >> 3) & 7)) * 8);
    const int soffV = (tid >> 4) * Tn + (((tid & 15) ^ ((tid >> 4) & 15)) * 8);

    auto prefetch = [&](int i, int buf) {
        u16* Kn = S_lds + buf * 8192;
        u16* Vn = S_lds + 16384 + buf * 8192;
        const u16* Kt = Kp + (long)i * 128 * 3072;
        const u16* Vg = Vp + i * 128;
#pragma unroll
        for (int j = 0; j < 2; ++j) {
            ldlds16(Kt + j * (64 * 3072) + soffK, Kn + j * 4096 + tid * 8);
            ldlds16(Vg + j * (32 * Tn) + soffV, Vn + j * 4096 + tid * 8);
        }
    };

    for (int job = 0; job < 2; ++job) {
        const int qt = job ? px : 31 - px;
        const u16* Qp = qkv + ((long)b * Tn + qt * 64) * 3072 + h * 64;

        // Q fragments (B-operand of S^T mfma): Q[q=mh16+lm][d=hh*32+g*8+j]
        short8 qa[2];
#pragma unroll
        for (int hh = 0; hh < 2; ++hh)
            qa[hh] = *(const short8*)(Qp + (mh16 + lm) * 3072 + hh * 32 + g * 8);

        f32x4 o_acc[4] = {};          // O^T[d=dt*16+g4+r][q=mh16+lm]
        float lsum = 0.f;
        const int qrow = qt * 64 + mh16 + lm;

        prefetch(0, 0);
        __syncthreads();

        auto body = [&](int buf, int sbase, auto diag_c) {
            constexpr bool DIAG = decltype(diag_c)::value;
            const u16* Kc = S_lds + buf * 8192;
            const u16* Vc = S_lds + 16384 + buf * 8192;
            // S^T = K * Q^T : 1 q-tile x 4 s-tiles, k=64
            f32x4 st[4];
#pragma unroll
            for (int nt = 0; nt < 4; ++nt)
                st[nt] = (f32x4){0.f, 0.f, 0.f, 0.f};
#pragma unroll
            for (int nt = 0; nt < 4; ++nt)
#pragma unroll
                for (int hh = 0; hh < 2; ++hh) {
                    short8 kf = *(const short8*)(Kc + (sh64 + nt * 16 + lm) * 64 +
                                                 (((hh * 4 + g) ^ lm7) * 8));
                    st[nt] = __builtin_amdgcn_mfma_f32_16x16x32_bf16(kf, qa[hh], st[nt], 0, 0, 0);
                }
            // exp2 + mask + pack to bf16 B-fragments (P^T stays in registers)
            short4v pb[4];
#pragma unroll
            for (int nt = 0; nt < 4; ++nt) {
                const int scolb = sbase + sh64 + nt * 16 + g4;
#pragma unroll
                for (int r = 0; r < 4; ++r) {
                    float xx = st[nt][r];
                    if (DIAG && scolb + r > qrow) xx = -1e30f;
                    float p = EXP2(xx);
                    lsum += p;
                    pb[nt][r] = (short)(__float_as_uint(p) >> 16);
                }
            }
            // O^T += V^T * P^T : per (s-16-chunk, d-tile) one 16x16x16 MFMA
#pragma unroll
            for (int nt = 0; nt < 4; ++nt) {
                const int vcol = (((sh8 + nt * 2 + (g >> 1)) ^ lm) * 8) + (g & 1) * 4;
#pragma unroll
                for (int dt = 0; dt < 4; ++dt) {
                    short4v vf = *(const short4v*)(Vc + (dt * 16 + lm) * 128 + vcol);
                    o_acc[dt] = __builtin_amdgcn_mfma_f32_16x16x16bf16_1k(vf, pb[nt], o_acc[dt], 0, 0, 0);
                }
            }
        };

        const int n = (qt >> 1) + 1;     // 128-col iterations; last is DIAG
        if (n == 1) {
            body(0, 0, TrueT{});
        } else {
            int i = 0;
            for (; i + 2 <= n - 1; i += 2) {
                prefetch(i + 1, 1); body(0, i * 128, FalseT{}); __syncthreads();
                prefetch(i + 2, 0); body(1, (i + 1) * 128, FalseT{}); __syncthreads();
            }
            if (i == n - 2) {
                prefetch(n - 1, 1); body(0, i * 128, FalseT{}); __syncthreads();
                body(1, (n - 1) * 128, TrueT{});
            } else {  // i == n-1
                body(0, i * 128, TrueT{});
            }
        }

        // rowsum: sum across the 4 quads holding the same q=lm
        lsum += __shfl_xor(lsum, 16, 64);
        lsum += __shfl_xor(lsum, 32, 64);

        // ---- epilogue: cross-sh reduce + transpose via padded f32 LDS ----
        __syncthreads();
        float* Ytf = (float*)S_lds;               // [64][68] f32 (17408 B)
        float* redl = (float*)(S_lds + 8704);     // 64 f32

        if (sh == 1) {
            const int q = mh16 + lm;
#pragma unroll
            for (int dt = 0; dt < 4; ++dt)
                *(f32x4*)(Ytf + q * 68 + dt * 16 + g4) = o_acc[dt];
            if (g == 0) redl[q] = lsum;
        }
        __syncthreads();
        if (sh == 0) {
            const int q = mh16 + lm;
            float inv = 1.0f / (lsum + redl[q]);
#pragma unroll
            for (int dt = 0; dt < 4; ++dt) {
                f32x4 t = *(const f32x4*)(Ytf + q * 68 + dt * 16 + g4);
                t += o_acc[dt];
                t *= inv;
                *(f32x4*)(Ytf + q * 68 + dt * 16 + g4) = t;
            }
        }
        __syncthreads();
        {   // coalesced store: 8 threads per q-row, 8 bf16 each
            const int q = tid >> 3, dseg = (tid & 7) * 8;
            long base = ((long)b * Tn + qt * 64 + q) * Cn + h * HDn + dseg;
            u16 tmp[8];
#pragma unroll
            for (int j = 0; j < 8; ++j)
                tmp[j] = f2bf(Ytf[q * 68 + dseg + j]);
            *(short8*)(Y + base) = *(const short8*)tmp;
        }
        __syncthreads();   // LDS reads done before next job restages
    }
}

extern "C" void kernel_launch(void* const* d_in, const int* in_sizes, int n_in,
                              void* d_out, int out_size, void* d_ws, size_t ws_size,
                              hipStream_t stream) {
    const float* x    = (const float*)d_in[0];
    const float* Wqkv = (const float*)d_in[1];
    const float* bqkv = (const float*)d_in[2];
    const float* Wo   = (const float*)d_in[3];
    const float* bo   = (const float*)d_in[4];
    float* out = (float*)d_out;

    u16* xb    = (u16*)d_ws;          // 4M u16 : x bf16
    u16* wqkvt = xb + 4194304;        // 3M : Wqkv^T
    u16* wot   = wqkvt + 3145728;     // 1M : Wo^T
    u16* qkvb  = wot + 1048576;       // 12M : qkv [b,t,3C] bf16 (Q pre-scaled; V third unused)
    u16* vtb   = qkvb + 12582912;     // 4M : V^T [b,h,d,t] (written by gemm_bt<0>)
    u16* yb    = vtb + 4194304;       // 4M : attn out [b,t,c]

    prep<<<5120, 256, 0, stream>>>(x, xb, Wqkv, wqkvt, Wo, wot);
    gemm_bt<0><<<dim3(32, 24), 256, 0, stream>>>(xb, wqkvt, bqkv, qkvb, vtb,
                                                 nullptr, 4096, 3072, 1024);
    attn<<<dim3(16, 32), 512, 0, stream>>>(qkvb, vtb, yb);
    gemm_bt64<<<dim3(64, 8), 512, 0, stream>>>(yb, wot, bo, out, 4096, 1024, 1024);
}

// Round 10
// 164.628 us; speedup vs baseline: 1.0201x; 1.0003x over previous
//
#include <hip/hip_runtime.h>

typedef unsigned short u16;
typedef __attribute__((ext_vector_type(8))) short short8;
typedef __attribute__((ext_vector_type(4))) short short4v;
typedef __attribute__((ext_vector_type(4))) float f32x4;
typedef __attribute__((ext_vector_type(4))) float float4v;
typedef __attribute__((ext_vector_type(4))) unsigned short u16x4;

#define AS1 __attribute__((address_space(1)))
#define AS3 __attribute__((address_space(3)))

// B=2, T=2048, C=1024, H=16, HD=64
#define Tn 2048
#define Cn 1024
#define Hn 16
#define HDn 64

#if __has_builtin(__builtin_amdgcn_exp2f)
#define EXP2(x) __builtin_amdgcn_exp2f(x)   // bare v_exp_f32 (no ocml denorm fixup)
#else
#define EXP2(x) exp2f(x)
#endif

struct FalseT { static constexpr bool value = false; };
struct TrueT  { static constexpr bool value = true;  };

static __device__ __forceinline__ u16 f2bf(float f) {
    unsigned int u = __float_as_uint(f);
    u += 0x7FFFu + ((u >> 16) & 1u);   // round-to-nearest-even
    return (u16)(u >> 16);
}

static __device__ __forceinline__ void ldlds16(const void* g, void* l) {
    __builtin_amdgcn_global_load_lds((const AS1 unsigned int*)g,
                                     (AS3 unsigned int*)l, 16, 0, 0);
}

// ---------------- fused prep: x->bf16 | Wqkv^T->bf16 | Wo^T->bf16 ----------------
__global__ void prep(const float* __restrict__ x, u16* __restrict__ xb,
                     const float* __restrict__ Wqkv, u16* __restrict__ wqkvt,
                     const float* __restrict__ Wo, u16* __restrict__ wot) {
    __shared__ float t[64][65];
    const int bx = blockIdx.x, tid = threadIdx.x;
    if (bx < 4096) {
        int i = bx * 256 + tid;
        float4v v = ((const float4v*)x)[i];
        u16x4 o;
        o.x = f2bf(v.x); o.y = f2bf(v.y); o.z = f2bf(v.z); o.w = f2bf(v.w);
        ((u16x4*)xb)[i] = o;
        return;
    }
    const float* in; u16* out; int R, Cc, r0, c0;
    if (bx < 4864) {
        int idx = bx - 4096;
        in = Wqkv; out = wqkvt; R = 1024; Cc = 3072;
        c0 = (idx % 48) * 64; r0 = (idx / 48) * 64;
    } else {
        int idx = bx - 4864;
        in = Wo; out = wot; R = 1024; Cc = 1024;
        c0 = (idx & 15) * 64; r0 = (idx >> 4) * 64;
    }
    int tx = tid & 63, ty = tid >> 6;
#pragma unroll
    for (int i = 0; i < 64; i += 4)
        t[ty + i][tx] = in[(long)(r0 + ty + i) * Cc + c0 + tx];
    __syncthreads();
#pragma unroll
    for (int i = 0; i < 64; i += 4)
        out[(long)(c0 + ty + i) * R + r0 + tx] = f2bf(t[tx][ty + i]);
}

// ---------------- m97-style GEMM, BK=64 (unchanged from R7, proven) ----------------
template <int MODE>
__global__ __launch_bounds__(256, 3)
void gemm_bt(const u16* __restrict__ A, const u16* __restrict__ Bt,
             const float* __restrict__ bias,
             u16* __restrict__ o16, u16* __restrict__ vout,
             float* __restrict__ f_out,
             int M, int N, int K) {
    __shared__ __attribute__((aligned(16))) u16 As[128 * 64];
    __shared__ __attribute__((aligned(16))) u16 Bs[128 * 64];
    const int tid = threadIdx.x;
    const int l = tid & 63;
    const int w = tid >> 6;
    const int wm = (w >> 1) * 64, wn = (w & 1) * 64;
    const long m0 = (long)blockIdx.x * 128, n0 = (long)blockIdx.y * 128;
    const int lm = l & 15, g = l >> 4;

    const int sr = tid >> 3;                         // 0..31 (row base, j adds 32)
    const int scx = (tid & 7) ^ ((tid >> 3) & 7);    // pre-swizzled col segment
    const u16* Ag = A + (m0 + sr) * K + scx * 8;
    const u16* Bg = Bt + (n0 + sr) * K + scx * 8;
    u16* Asl = As + tid * 8;
    u16* Bsl = Bs + tid * 8;
    const int xr = lm & 7;                           // read-side row XOR

    f32x4 acc[4][4] = {};

    for (int k0 = 0; k0 < K; k0 += 64) {
        __syncthreads();
#pragma unroll
        for (int j = 0; j < 4; ++j) {
            ldlds16(Ag + k0 + (long)(j * 32) * K, Asl + j * 2048);
            ldlds16(Bg + k0 + (long)(j * 32) * K, Bsl + j * 2048);
        }
        __syncthreads();
#pragma unroll
        for (int kk = 0; kk < 2; ++kk) {
            const int cs0 = ((kk * 4 + g) ^ xr) * 8;
            short8 af[4], bf[4];
#pragma unroll
            for (int mt = 0; mt < 4; ++mt)
                af[mt] = *(const short8*)(As + (wm + mt * 16 + lm) * 64 + cs0);
#pragma unroll
            for (int nt = 0; nt < 4; ++nt)
                bf[nt] = *(const short8*)(Bs + (wn + nt * 16 + lm) * 64 + cs0);
#pragma unroll
            for (int mt = 0; mt < 4; ++mt)
#pragma unroll
                for (int nt = 0; nt < 4; ++nt)
                    acc[mt][nt] = __builtin_amdgcn_mfma_f32_16x16x32_bf16(
                        af[mt], bf[nt], acc[mt][nt], 0, 0, 0);
        }
    }

    if (MODE == 0 && n0 >= 2048) {
        // ---- fused V^T emit: transpose 128x128 tile via LDS (As), 2 passes ----
        const long b = m0 >> 11;
        const int t0 = (int)(m0 & 2047);
        const int n0b = (int)(n0 - 2048);
#pragma unroll
        for (int p = 0; p < 2; ++p) {
            __syncthreads();               // prior LDS reads (k-loop / pass p-1) done
            if ((w & 1) == p) {            // waves whose wn == p*64 hold this n-half
#pragma unroll
                for (int mt = 0; mt < 4; ++mt) {
                    const int colu = wm + mt * 16 + g * 4;   // m_local base (4-aligned)
#pragma unroll
                    for (int nt = 0; nt < 4; ++nt) {
                        const int row = nt * 16 + lm;        // n_local in 0..63
                        float bv = bias[n0 + p * 64 + row];
                        u16 tmp[4];
#pragma unroll
                        for (int r = 0; r < 4; ++r)
                            tmp[r] = f2bf(acc[mt][nt][r] + bv);
                        // XOR-swizzle columns by row to avoid 16-way write conflicts
                        *(u16x4*)(As + row * 128 + (colu ^ (lm << 3))) = *(const u16x4*)tmp;
                    }
                }
            }
            __syncthreads();
            {   // coalesced V^T store: 4 threads per n-row, 64B each along t
                const int nl = tid >> 2, mb = (tid & 3) * 32;
                const int ng = n0b + p * 64 + nl;
                u16* dst = vout + (((b * 16 + (ng >> 6)) * 64 + (ng & 63)) * (long)Tn) + t0;
#pragma unroll
                for (int j = 0; j < 4; ++j) {
                    const int c = mb + j * 8;
                    *(short8*)(dst + c) =
                        *(const short8*)(As + nl * 128 + (c ^ ((nl & 15) << 3)));
                }
            }
        }
        return;
    }

    const int r0 = (l >> 4) * 4;
#pragma unroll
    for (int mt = 0; mt < 4; ++mt) {
#pragma unroll
        for (int nt = 0; nt < 4; ++nt) {
            long n = n0 + wn + nt * 16 + lm;
            float bv = bias[n];
            // fold softmax scale (0.125*log2e) into Q columns at MODE 0
            float scq = (MODE == 0 && n < 1024) ? 0.18033688f : 1.0f;
#pragma unroll
            for (int r = 0; r < 4; ++r) {
                long m = m0 + wm + mt * 16 + r0 + r;
                float v = (acc[mt][nt][r] + bv) * scq;
                if (MODE == 0) o16[m * N + n] = f2bf(v);
                else           f_out[m * N + n] = v;
            }
        }
    }
}

// ---------------- 64x128-tile fp32-out GEMM (Wo projection), 512-thread, BK=64 ----
// (unchanged from R9, proven)
__global__ __launch_bounds__(512, 2)
void gemm_bt64(const u16* __restrict__ A, const u16* __restrict__ Bt,
               const float* __restrict__ bias, float* __restrict__ f_out,
               int M, int N, int K) {
    __shared__ __attribute__((aligned(16))) u16 As[64 * 64];
    __shared__ __attribute__((aligned(16))) u16 Bs[128 * 64];
    const int tid = threadIdx.x;          // 0..511
    const int l = tid & 63;
    const int w = tid >> 6;               // 0..7
    const int wm = (w & 1) * 32, wn = (w >> 1) * 32;
    const long m0 = (long)blockIdx.x * 64, n0 = (long)blockIdx.y * 128;
    const int lm = l & 15, g = l >> 4;

    const int sr = tid >> 3;                         // 0..63
    const int scx = (tid & 7) ^ ((tid >> 3) & 7);    // pre-swizzled col segment
    const u16* Ag = A + (m0 + sr) * K + scx * 8;
    const u16* Bg = Bt + (n0 + sr) * K + scx * 8;    // row +64 adds 64*K, same swz (&7)
    u16* Asl = As + tid * 8;
    u16* Bsl = Bs + tid * 8;
    const int xr = lm & 7;

    f32x4 acc[2][2] = {};

    for (int k0 = 0; k0 < K; k0 += 64) {
        __syncthreads();
        ldlds16(Ag + k0, Asl);
        ldlds16(Bg + k0, Bsl);
        ldlds16(Bg + k0 + (long)64 * K, Bsl + 4096);
        __syncthreads();
#pragma unroll
        for (int kk = 0; kk < 2; ++kk) {
            const int cs0 = ((kk * 4 + g) ^ xr) * 8;
            short8 af[2], bf[2];
#pragma unroll
            for (int mt = 0; mt < 2; ++mt)
                af[mt] = *(const short8*)(As + (wm + mt * 16 + lm) * 64 + cs0);
#pragma unroll
            for (int nt = 0; nt < 2; ++nt)
                bf[nt] = *(const short8*)(Bs + (wn + nt * 16 + lm) * 64 + cs0);
#pragma unroll
            for (int mt = 0; mt < 2; ++mt)
#pragma unroll
                for (int nt = 0; nt < 2; ++nt)
                    acc[mt][nt] = __builtin_amdgcn_mfma_f32_16x16x32_bf16(
                        af[mt], bf[nt], acc[mt][nt], 0, 0, 0);
        }
    }

    const int r0 = g * 4;
#pragma unroll
    for (int mt = 0; mt < 2; ++mt) {
#pragma unroll
        for (int nt = 0; nt < 2; ++nt) {
            long n = n0 + wn + nt * 16 + lm;
            float bv = bias[n];
#pragma unroll
            for (int r = 0; r < 4; ++r) {
                long m = m0 + wm + mt * 16 + r0 + r;
                f_out[m * N + n] = acc[mt][nt][r] + bv;
            }
        }
    }
}

// ---------------- flash attention: S^T formulation, 64-col windows ----------------
// R10: s-window 128 -> 64 cols. K tile 64x64, V tile 64x64, double-buffered =
// 32KB LDS -> 4 blocks/CU (was 2) = 32 waves/CU = 100% wave cap. attn's counter
// signature (MfmaUtil 25 / VALUBusy 48 / Occ 32 / HBM 6%) is latency-bound; the
// fix is occupancy, not issue-count. MFMA/exp totals unchanged; windows/block
// 17 -> 33 (barrier waits now overlap across 4 resident blocks).
// Per-window: QK 4 MFMA, exp 8, PV 8 MFMA. Swizzle re-derived for 64-wide tiles
// (3-bit seg field; V-read XOR partner lm&7; both-sides involution).
// LDS 32 KB: Ks[2] 64x64 @0/4096, Vs[2] 64x64 @8192/12288 (u16 idx).
__global__ __launch_bounds__(512, 4)
void attn(const u16* __restrict__ qkv, const u16* __restrict__ Vt,
          u16* __restrict__ Y) {
    __shared__ __attribute__((aligned(16))) u16 S_lds[16384];

    // XCD swizzle: lin = hw linear block id; residue class (lin&7) -> 64 blocks
    // = bh in [4c, 4c+4) x px 0..15, all co-resident on one XCD.
    const int lin = blockIdx.x + (blockIdx.y << 4);
    const int s = (lin & 7) * 64 + (lin >> 3);
    const int px = s & 15;                 // 0..15
    const int bh = s >> 4;                 // 0..31
    const int tid = threadIdx.x, l = tid & 63, w = tid >> 6;   // w 0..7
    const int mh = w >> 1, sh = w & 1;
    const int lm = l & 15, g = l >> 4;
    const int lm7 = lm & 7;
    const int mh16 = mh * 16, sh32 = sh * 32, g4 = g * 4;
    const int b = bh >> 4, h = bh & 15;

    const u16* Kp = qkv + (long)b * Tn * 3072 + 1024 + h * 64;
    const u16* Vp = Vt + (long)bh * HDn * Tn;

    // staging: one ldlds16/thread per operand; row=tid>>3, seg=(tid&7)^(row&7)
    const int soffK = (tid >> 3) * 3072 + (((tid & 7) ^ ((tid >> 3) & 7)) * 8);
    const int soffV = (tid >> 3) * Tn + (((tid & 7) ^ ((tid >> 3) & 7)) * 8);

    auto prefetch = [&](int i, int buf) {
        ldlds16(Kp + (long)i * 64 * 3072 + soffK, S_lds + buf * 4096 + tid * 8);
        ldlds16(Vp + i * 64 + soffV, S_lds + 8192 + buf * 4096 + tid * 8);
    };

    for (int job = 0; job < 2; ++job) {
        const int qt = job ? px : 31 - px;
        const u16* Qp = qkv + ((long)b * Tn + qt * 64) * 3072 + h * 64;

        // Q fragments (B-operand of S^T mfma): Q[q=mh16+lm][d=hh*32+g*8+j]
        short8 qa[2];
#pragma unroll
        for (int hh = 0; hh < 2; ++hh)
            qa[hh] = *(const short8*)(Qp + (mh16 + lm) * 3072 + hh * 32 + g * 8);

        f32x4 o_acc[4] = {};          // O^T[d=dt*16+g4+r][q=mh16+lm]
        float lsum = 0.f;
        const int qrow = qt * 64 + mh16 + lm;

        prefetch(0, 0);
        __syncthreads();

        auto body = [&](int buf, int sbase, auto diag_c) {
            constexpr bool DIAG = decltype(diag_c)::value;
            const u16* Kc = S_lds + buf * 4096;
            const u16* Vc = S_lds + 8192 + buf * 4096;
            // S^T = K * Q^T : 1 q-tile x 2 s-tiles, k=64
            f32x4 st[2];
#pragma unroll
            for (int nt = 0; nt < 2; ++nt)
                st[nt] = (f32x4){0.f, 0.f, 0.f, 0.f};
#pragma unroll
            for (int nt = 0; nt < 2; ++nt)
#pragma unroll
                for (int hh = 0; hh < 2; ++hh) {
                    short8 kf = *(const short8*)(Kc + (sh32 + nt * 16 + lm) * 64 +
                                                 (((hh * 4 + g) ^ lm7) * 8));
                    st[nt] = __builtin_amdgcn_mfma_f32_16x16x32_bf16(kf, qa[hh], st[nt], 0, 0, 0);
                }
            // exp2 + mask + pack to bf16 B-fragments (P^T stays in registers)
            short4v pb[2];
#pragma unroll
            for (int nt = 0; nt < 2; ++nt) {
                const int scolb = sbase + sh32 + nt * 16 + g4;
#pragma unroll
                for (int r = 0; r < 4; ++r) {
                    float xx = st[nt][r];
                    if (DIAG && scolb + r > qrow) xx = -1e30f;
                    float p = EXP2(xx);
                    lsum += p;
                    pb[nt][r] = (short)(__float_as_uint(p) >> 16);
                }
            }
            // O^T += V^T * P^T : per (s-16-chunk, d-tile) one 16x16x16 MFMA
#pragma unroll
            for (int nt = 0; nt < 2; ++nt) {
                const int vcol = (((sh * 4 + nt * 2 + (g >> 1)) ^ lm7) * 8) + (g & 1) * 4;
#pragma unroll
                for (int dt = 0; dt < 4; ++dt) {
                    short4v vf = *(const short4v*)(Vc + (dt * 16 + lm) * 64 + vcol);
                    o_acc[dt] = __builtin_amdgcn_mfma_f32_16x16x16bf16_1k(vf, pb[nt], o_acc[dt], 0, 0, 0);
                }
            }
        };

        const int n = qt + 1;            // 64-col windows; last is DIAG
        if (n == 1) {
            body(0, 0, TrueT{});
        } else {
            int i = 0;
            for (; i + 2 <= n - 1; i += 2) {
                prefetch(i + 1, 1); body(0, i * 64, FalseT{}); __syncthreads();
                prefetch(i + 2, 0); body(1, (i + 1) * 64, FalseT{}); __syncthreads();
            }
            if (i == n - 2) {
                prefetch(n - 1, 1); body(0, i * 64, FalseT{}); __syncthreads();
                body(1, (n - 1) * 64, TrueT{});
            } else {  // i == n-1
                body(0, i * 64, TrueT{});
            }
        }

        // rowsum: sum across the 4 quads holding the same q=lm
        lsum += __shfl_xor(lsum, 16, 64);
        lsum += __shfl_xor(lsum, 32, 64);

        // ---- epilogue: cross-sh reduce + transpose via padded f32 LDS ----
        __syncthreads();
        float* Ytf = (float*)S_lds;               // [64][68] f32 (17408 B)
        float* redl = (float*)(S_lds + 8704);     // 64 f32 @byte 17408

        if (sh == 1) {
            const int q = mh16 + lm;
#pragma unroll
            for (int dt = 0; dt < 4; ++dt)
                *(f32x4*)(Ytf + q * 68 + dt * 16 + g4) = o_acc[dt];
            if (g == 0) redl[q] = lsum;
        }
        __syncthreads();
        if (sh == 0) {
            const int q = mh16 + lm;
            float inv = 1.0f / (lsum + redl[q]);
#pragma unroll
            for (int dt = 0; dt < 4; ++dt) {
                f32x4 t = *(const f32x4*)(Ytf + q * 68 + dt * 16 + g4);
                t += o_acc[dt];
                t *= inv;
                *(f32x4*)(Ytf + q * 68 + dt * 16 + g4) = t;
            }
        }
        __syncthreads();
        {   // coalesced store: 8 threads per q-row, 8 bf16 each
            const int q = tid >> 3, dseg = (tid & 7) * 8;
            long base = ((long)b * Tn + qt * 64 + q) * Cn + h * HDn + dseg;
            u16 tmp[8];
#pragma unroll
            for (int j = 0; j < 8; ++j)
                tmp[j] = f2bf(Ytf[q * 68 + dseg + j]);
            *(short8*)(Y + base) = *(const short8*)tmp;
        }
        __syncthreads();   // LDS reads done before next job restages
    }
}

extern "C" void kernel_launch(void* const* d_in, const int* in_sizes, int n_in,
                              void* d_out, int out_size, void* d_ws, size_t ws_size,
                              hipStream_t stream) {
    const float* x    = (const float*)d_in[0];
    const float* Wqkv = (const float*)d_in[1];
    const float* bqkv = (const float*)d_in[2];
    const float* Wo   = (const float*)d_in[3];
    const float* bo   = (const float*)d_in[4];
    float* out = (float*)d_out;

    u16* xb    = (u16*)d_ws;          // 4M u16 : x bf16
    u16* wqkvt = xb + 4194304;        // 3M : Wqkv^T
    u16* wot   = wqkvt + 3145728;     // 1M : Wo^T
    u16* qkvb  = wot + 1048576;       // 12M : qkv [b,t,3C] bf16 (Q pre-scaled; V third unused)
    u16* vtb   = qkvb + 12582912;     // 4M : V^T [b,h,d,t] (written by gemm_bt<0>)
    u16* yb    = vtb + 4194304;       // 4M : attn out [b,t,c]

    prep<<<5120, 256, 0, stream>>>(x, xb, Wqkv, wqkvt, Wo, wot);
    gemm_bt<0><<<dim3(32, 24), 256, 0, stream>>>(xb, wqkvt, bqkv, qkvb, vtb,
                                                 nullptr, 4096, 3072, 1024);
    attn<<<dim3(16, 32), 512, 0, stream>>>(qkvb, vtb, yb);
    gemm_bt64<<<dim3(64, 8), 512, 0, stream>>>(yb, wot, bo, out, 4096, 1024, 1024);
}

// Round 11
// 159.707 us; speedup vs baseline: 1.0515x; 1.0308x over previous
//
#include <hip/hip_runtime.h>

typedef unsigned short u16;
typedef __attribute__((ext_vector_type(8))) short short8;
typedef __attribute__((ext_vector_type(4))) short short4v;
typedef __attribute__((ext_vector_type(4))) float f32x4;
typedef __attribute__((ext_vector_type(4))) float float4v;
typedef __attribute__((ext_vector_type(4))) unsigned short u16x4;

#define AS1 __attribute__((address_space(1)))
#define AS3 __attribute__((address_space(3)))

// B=2, T=2048, C=1024, H=16, HD=64
#define Tn 2048
#define Cn 1024
#define Hn 16
#define HDn 64

#if __has_builtin(__builtin_amdgcn_exp2f)
#define EXP2(x) __builtin_amdgcn_exp2f(x)   // bare v_exp_f32 (no ocml denorm fixup)
#else
#define EXP2(x) exp2f(x)
#endif

struct FalseT { static constexpr bool value = false; };
struct TrueT  { static constexpr bool value = true;  };

static __device__ __forceinline__ u16 f2bf(float f) {
    unsigned int u = __float_as_uint(f);
    u += 0x7FFFu + ((u >> 16) & 1u);   // round-to-nearest-even
    return (u16)(u >> 16);
}

static __device__ __forceinline__ void ldlds16(const void* g, void* l) {
    __builtin_amdgcn_global_load_lds((const AS1 unsigned int*)g,
                                     (AS3 unsigned int*)l, 16, 0, 0);
}

// ---------------- fused prep: x->bf16 | Wqkv^T->bf16 | Wo^T->bf16 ----------------
__global__ void prep(const float* __restrict__ x, u16* __restrict__ xb,
                     const float* __restrict__ Wqkv, u16* __restrict__ wqkvt,
                     const float* __restrict__ Wo, u16* __restrict__ wot) {
    __shared__ float t[64][65];
    const int bx = blockIdx.x, tid = threadIdx.x;
    if (bx < 4096) {
        int i = bx * 256 + tid;
        float4v v = ((const float4v*)x)[i];
        u16x4 o;
        o.x = f2bf(v.x); o.y = f2bf(v.y); o.z = f2bf(v.z); o.w = f2bf(v.w);
        ((u16x4*)xb)[i] = o;
        return;
    }
    const float* in; u16* out; int R, Cc, r0, c0;
    if (bx < 4864) {
        int idx = bx - 4096;
        in = Wqkv; out = wqkvt; R = 1024; Cc = 3072;
        c0 = (idx % 48) * 64; r0 = (idx / 48) * 64;
    } else {
        int idx = bx - 4864;
        in = Wo; out = wot; R = 1024; Cc = 1024;
        c0 = (idx & 15) * 64; r0 = (idx >> 4) * 64;
    }
    int tx = tid & 63, ty = tid >> 6;
#pragma unroll
    for (int i = 0; i < 64; i += 4)
        t[ty + i][tx] = in[(long)(r0 + ty + i) * Cc + c0 + tx];
    __syncthreads();
#pragma unroll
    for (int i = 0; i < 64; i += 4)
        out[(long)(c0 + ty + i) * R + r0 + tx] = f2bf(t[tx][ty + i]);
}

// ---------------- m97-style GEMM, BK=64 (unchanged from R7, proven) ----------------
template <int MODE>
__global__ __launch_bounds__(256, 3)
void gemm_bt(const u16* __restrict__ A, const u16* __restrict__ Bt,
             const float* __restrict__ bias,
             u16* __restrict__ o16, u16* __restrict__ vout,
             float* __restrict__ f_out,
             int M, int N, int K) {
    __shared__ __attribute__((aligned(16))) u16 As[128 * 64];
    __shared__ __attribute__((aligned(16))) u16 Bs[128 * 64];
    const int tid = threadIdx.x;
    const int l = tid & 63;
    const int w = tid >> 6;
    const int wm = (w >> 1) * 64, wn = (w & 1) * 64;
    const long m0 = (long)blockIdx.x * 128, n0 = (long)blockIdx.y * 128;
    const int lm = l & 15, g = l >> 4;

    const int sr = tid >> 3;                         // 0..31 (row base, j adds 32)
    const int scx = (tid & 7) ^ ((tid >> 3) & 7);    // pre-swizzled col segment
    const u16* Ag = A + (m0 + sr) * K + scx * 8;
    const u16* Bg = Bt + (n0 + sr) * K + scx * 8;
    u16* Asl = As + tid * 8;
    u16* Bsl = Bs + tid * 8;
    const int xr = lm & 7;                           // read-side row XOR

    f32x4 acc[4][4] = {};

    for (int k0 = 0; k0 < K; k0 += 64) {
        __syncthreads();
#pragma unroll
        for (int j = 0; j < 4; ++j) {
            ldlds16(Ag + k0 + (long)(j * 32) * K, Asl + j * 2048);
            ldlds16(Bg + k0 + (long)(j * 32) * K, Bsl + j * 2048);
        }
        __syncthreads();
#pragma unroll
        for (int kk = 0; kk < 2; ++kk) {
            const int cs0 = ((kk * 4 + g) ^ xr) * 8;
            short8 af[4], bf[4];
#pragma unroll
            for (int mt = 0; mt < 4; ++mt)
                af[mt] = *(const short8*)(As + (wm + mt * 16 + lm) * 64 + cs0);
#pragma unroll
            for (int nt = 0; nt < 4; ++nt)
                bf[nt] = *(const short8*)(Bs + (wn + nt * 16 + lm) * 64 + cs0);
#pragma unroll
            for (int mt = 0; mt < 4; ++mt)
#pragma unroll
                for (int nt = 0; nt < 4; ++nt)
                    acc[mt][nt] = __builtin_amdgcn_mfma_f32_16x16x32_bf16(
                        af[mt], bf[nt], acc[mt][nt], 0, 0, 0);
        }
    }

    if (MODE == 0 && n0 >= 2048) {
        // ---- fused V^T emit: transpose 128x128 tile via LDS (As), 2 passes ----
        const long b = m0 >> 11;
        const int t0 = (int)(m0 & 2047);
        const int n0b = (int)(n0 - 2048);
#pragma unroll
        for (int p = 0; p < 2; ++p) {
            __syncthreads();               // prior LDS reads (k-loop / pass p-1) done
            if ((w & 1) == p) {            // waves whose wn == p*64 hold this n-half
#pragma unroll
                for (int mt = 0; mt < 4; ++mt) {
                    const int colu = wm + mt * 16 + g * 4;   // m_local base (4-aligned)
#pragma unroll
                    for (int nt = 0; nt < 4; ++nt) {
                        const int row = nt * 16 + lm;        // n_local in 0..63
                        float bv = bias[n0 + p * 64 + row];
                        u16 tmp[4];
#pragma unroll
                        for (int r = 0; r < 4; ++r)
                            tmp[r] = f2bf(acc[mt][nt][r] + bv);
                        // XOR-swizzle columns by row to avoid 16-way write conflicts
                        *(u16x4*)(As + row * 128 + (colu ^ (lm << 3))) = *(const u16x4*)tmp;
                    }
                }
            }
            __syncthreads();
            {   // coalesced V^T store: 4 threads per n-row, 64B each along t
                const int nl = tid >> 2, mb = (tid & 3) * 32;
                const int ng = n0b + p * 64 + nl;
                u16* dst = vout + (((b * 16 + (ng >> 6)) * 64 + (ng & 63)) * (long)Tn) + t0;
#pragma unroll
                for (int j = 0; j < 4; ++j) {
                    const int c = mb + j * 8;
                    *(short8*)(dst + c) =
                        *(const short8*)(As + nl * 128 + (c ^ ((nl & 15) << 3)));
                }
            }
        }
        return;
    }

    const int r0 = (l >> 4) * 4;
#pragma unroll
    for (int mt = 0; mt < 4; ++mt) {
#pragma unroll
        for (int nt = 0; nt < 4; ++nt) {
            long n = n0 + wn + nt * 16 + lm;
            float bv = bias[n];
            // fold softmax scale (0.125*log2e) into Q columns at MODE 0
            float scq = (MODE == 0 && n < 1024) ? 0.18033688f : 1.0f;
#pragma unroll
            for (int r = 0; r < 4; ++r) {
                long m = m0 + wm + mt * 16 + r0 + r;
                float v = (acc[mt][nt][r] + bv) * scq;
                if (MODE == 0) o16[m * N + n] = f2bf(v);
                else           f_out[m * N + n] = v;
            }
        }
    }
}

// ---------------- 64x128-tile fp32-out GEMM (Wo projection), 512-thread, BK=64 ----
// (unchanged from R9, proven)
__global__ __launch_bounds__(512, 2)
void gemm_bt64(const u16* __restrict__ A, const u16* __restrict__ Bt,
               const float* __restrict__ bias, float* __restrict__ f_out,
               int M, int N, int K) {
    __shared__ __attribute__((aligned(16))) u16 As[64 * 64];
    __shared__ __attribute__((aligned(16))) u16 Bs[128 * 64];
    const int tid = threadIdx.x;          // 0..511
    const int l = tid & 63;
    const int w = tid >> 6;               // 0..7
    const int wm = (w & 1) * 32, wn = (w >> 1) * 32;
    const long m0 = (long)blockIdx.x * 64, n0 = (long)blockIdx.y * 128;
    const int lm = l & 15, g = l >> 4;

    const int sr = tid >> 3;                         // 0..63
    const int scx = (tid & 7) ^ ((tid >> 3) & 7);    // pre-swizzled col segment
    const u16* Ag = A + (m0 + sr) * K + scx * 8;
    const u16* Bg = Bt + (n0 + sr) * K + scx * 8;    // row +64 adds 64*K, same swz (&7)
    u16* Asl = As + tid * 8;
    u16* Bsl = Bs + tid * 8;
    const int xr = lm & 7;

    f32x4 acc[2][2] = {};

    for (int k0 = 0; k0 < K; k0 += 64) {
        __syncthreads();
        ldlds16(Ag + k0, Asl);
        ldlds16(Bg + k0, Bsl);
        ldlds16(Bg + k0 + (long)64 * K, Bsl + 4096);
        __syncthreads();
#pragma unroll
        for (int kk = 0; kk < 2; ++kk) {
            const int cs0 = ((kk * 4 + g) ^ xr) * 8;
            short8 af[2], bf[2];
#pragma unroll
            for (int mt = 0; mt < 2; ++mt)
                af[mt] = *(const short8*)(As + (wm + mt * 16 + lm) * 64 + cs0);
#pragma unroll
            for (int nt = 0; nt < 2; ++nt)
                bf[nt] = *(const short8*)(Bs + (wn + nt * 16 + lm) * 64 + cs0);
#pragma unroll
            for (int mt = 0; mt < 2; ++mt)
#pragma unroll
                for (int nt = 0; nt < 2; ++nt)
                    acc[mt][nt] = __builtin_amdgcn_mfma_f32_16x16x32_bf16(
                        af[mt], bf[nt], acc[mt][nt], 0, 0, 0);
        }
    }

    const int r0 = g * 4;
#pragma unroll
    for (int mt = 0; mt < 2; ++mt) {
#pragma unroll
        for (int nt = 0; nt < 2; ++nt) {
            long n = n0 + wn + nt * 16 + lm;
            float bv = bias[n];
#pragma unroll
            for (int r = 0; r < 4; ++r) {
                long m = m0 + wm + mt * 16 + r0 + r;
                f_out[m * N + n] = acc[mt][nt][r] + bv;
            }
        }
    }
}

// ---------------- flash attention: S^T formulation, 64-col windows ----------------
// R11: R10 structure with a relaxed register cap. (512,3) -> ~85-VGPR budget
// (was 64-cap at (512,4), compiled exactly AT the cap every round -- suspected
// schedule-serializing). Occupancy drops 4->3 blocks/CU, which R9-vs-R10 showed
// is a free axis (2 vs 4 blocks/CU measured identical). Headroom used to hoist
// BOTH jobs' Q fragments above the job loop (job-1 Q load latency previously
// exposed at the job boundary; +8 VGPR). Epilogue store reads via f32x4.
// Per-window: QK 4 MFMA, exp 8, PV 8 MFMA; windows/block 33.
// LDS 32 KB: Ks[2] 64x64 @0/4096, Vs[2] 64x64 @8192/12288 (u16 idx).
__global__ __launch_bounds__(512, 3)
void attn(const u16* __restrict__ qkv, const u16* __restrict__ Vt,
          u16* __restrict__ Y) {
    __shared__ __attribute__((aligned(16))) u16 S_lds[16384];

    // XCD swizzle: lin = hw linear block id; residue class (lin&7) -> 64 blocks
    // = bh in [4c, 4c+4) x px 0..15, all co-resident on one XCD.
    const int lin = blockIdx.x + (blockIdx.y << 4);
    const int s = (lin & 7) * 64 + (lin >> 3);
    const int px = s & 15;                 // 0..15
    const int bh = s >> 4;                 // 0..31
    const int tid = threadIdx.x, l = tid & 63, w = tid >> 6;   // w 0..7
    const int mh = w >> 1, sh = w & 1;
    const int lm = l & 15, g = l >> 4;
    const int lm7 = lm & 7;
    const int mh16 = mh * 16, sh32 = sh * 32, g4 = g * 4;
    const int b = bh >> 4, h = bh & 15;

    const u16* Kp = qkv + (long)b * Tn * 3072 + 1024 + h * 64;
    const u16* Vp = Vt + (long)bh * HDn * Tn;

    // staging: one ldlds16/thread per operand; row=tid>>3, seg=(tid&7)^(row&7)
    const int soffK = (tid >> 3) * 3072 + (((tid & 7) ^ ((tid >> 3) & 7)) * 8);
    const int soffV = (tid >> 3) * Tn + (((tid & 7) ^ ((tid >> 3) & 7)) * 8);

    auto prefetch = [&](int i, int buf) {
        ldlds16(Kp + (long)i * 64 * 3072 + soffK, S_lds + buf * 4096 + tid * 8);
        ldlds16(Vp + i * 64 + soffV, S_lds + 8192 + buf * 4096 + tid * 8);
    };

    // hoist BOTH jobs' Q fragments: Q[q=mh16+lm][d=hh*32+g*8+j]
    short8 qaJ[2][2];
#pragma unroll
    for (int job = 0; job < 2; ++job) {
        const int qt = job ? px : 31 - px;
        const u16* Qp = qkv + ((long)b * Tn + qt * 64) * 3072 + h * 64;
#pragma unroll
        for (int hh = 0; hh < 2; ++hh)
            qaJ[job][hh] = *(const short8*)(Qp + (mh16 + lm) * 3072 + hh * 32 + g * 8);
    }

    for (int job = 0; job < 2; ++job) {
        const int qt = job ? px : 31 - px;
        short8 qa[2] = {qaJ[job][0], qaJ[job][1]};

        f32x4 o_acc[4] = {};          // O^T[d=dt*16+g4+r][q=mh16+lm]
        float lsum = 0.f;
        const int qrow = qt * 64 + mh16 + lm;

        prefetch(0, 0);
        __syncthreads();

        auto body = [&](int buf, int sbase, auto diag_c) {
            constexpr bool DIAG = decltype(diag_c)::value;
            const u16* Kc = S_lds + buf * 4096;
            const u16* Vc = S_lds + 8192 + buf * 4096;
            // S^T = K * Q^T : 1 q-tile x 2 s-tiles, k=64
            f32x4 st[2];
#pragma unroll
            for (int nt = 0; nt < 2; ++nt)
                st[nt] = (f32x4){0.f, 0.f, 0.f, 0.f};
#pragma unroll
            for (int nt = 0; nt < 2; ++nt)
#pragma unroll
                for (int hh = 0; hh < 2; ++hh) {
                    short8 kf = *(const short8*)(Kc + (sh32 + nt * 16 + lm) * 64 +
                                                 (((hh * 4 + g) ^ lm7) * 8));
                    st[nt] = __builtin_amdgcn_mfma_f32_16x16x32_bf16(kf, qa[hh], st[nt], 0, 0, 0);
                }
            // exp2 + mask + pack to bf16 B-fragments (P^T stays in registers)
            short4v pb[2];
#pragma unroll
            for (int nt = 0; nt < 2; ++nt) {
                const int scolb = sbase + sh32 + nt * 16 + g4;
#pragma unroll
                for (int r = 0; r < 4; ++r) {
                    float xx = st[nt][r];
                    if (DIAG && scolb + r > qrow) xx = -1e30f;
                    float p = EXP2(xx);
                    lsum += p;
                    pb[nt][r] = (short)(__float_as_uint(p) >> 16);
                }
            }
            // O^T += V^T * P^T : per (s-16-chunk, d-tile) one 16x16x16 MFMA
#pragma unroll
            for (int nt = 0; nt < 2; ++nt) {
                const int vcol = (((sh * 4 + nt * 2 + (g >> 1)) ^ lm7) * 8) + (g & 1) * 4;
#pragma unroll
                for (int dt = 0; dt < 4; ++dt) {
                    short4v vf = *(const short4v*)(Vc + (dt * 16 + lm) * 64 + vcol);
                    o_acc[dt] = __builtin_amdgcn_mfma_f32_16x16x16bf16_1k(vf, pb[nt], o_acc[dt], 0, 0, 0);
                }
            }
        };

        const int n = qt + 1;            // 64-col windows; last is DIAG
        if (n == 1) {
            body(0, 0, TrueT{});
        } else {
            int i = 0;
            for (; i + 2 <= n - 1; i += 2) {
                prefetch(i + 1, 1); body(0, i * 64, FalseT{}); __syncthreads();
                prefetch(i + 2, 0); body(1, (i + 1) * 64, FalseT{}); __syncthreads();
            }
            if (i == n - 2) {
                prefetch(n - 1, 1); body(0, i * 64, FalseT{}); __syncthreads();
                body(1, (n - 1) * 64, TrueT{});
            } else {  // i == n-1
                body(0, i * 64, TrueT{});
            }
        }

        // rowsum: sum across the 4 quads holding the same q=lm
        lsum += __shfl_xor(lsum, 16, 64);
        lsum += __shfl_xor(lsum, 32, 64);

        // ---- epilogue: cross-sh reduce + transpose via padded f32 LDS ----
        __syncthreads();
        float* Ytf = (float*)S_lds;               // [64][68] f32 (17408 B)
        float* redl = (float*)(S_lds + 8704);     // 64 f32 @byte 17408

        if (sh == 1) {
            const int q = mh16 + lm;
#pragma unroll
            for (int dt = 0; dt < 4; ++dt)
                *(f32x4*)(Ytf + q * 68 + dt * 16 + g4) = o_acc[dt];
            if (g == 0) redl[q] = lsum;
        }
        __syncthreads();
        if (sh == 0) {
            const int q = mh16 + lm;
            float inv = 1.0f / (lsum + redl[q]);
#pragma unroll
            for (int dt = 0; dt < 4; ++dt) {
                f32x4 t = *(const f32x4*)(Ytf + q * 68 + dt * 16 + g4);
                t += o_acc[dt];
                t *= inv;
                *(f32x4*)(Ytf + q * 68 + dt * 16 + g4) = t;
            }
        }
        __syncthreads();
        {   // coalesced store: 8 threads per q-row, 8 bf16 each (f32x4 LDS reads)
            const int q = tid >> 3, dseg = (tid & 7) * 8;
            long base = ((long)b * Tn + qt * 64 + q) * Cn + h * HDn + dseg;
            f32x4 v0 = *(const f32x4*)(Ytf + q * 68 + dseg);
            f32x4 v1 = *(const f32x4*)(Ytf + q * 68 + dseg + 4);
            u16 tmp[8];
#pragma unroll
            for (int j = 0; j < 4; ++j) { tmp[j] = f2bf(v0[j]); tmp[4 + j] = f2bf(v1[j]); }
            *(short8*)(Y + base) = *(const short8*)tmp;
        }
        __syncthreads();   // LDS reads done before next job restages
    }
}

extern "C" void kernel_launch(void* const* d_in, const int* in_sizes, int n_in,
                              void* d_out, int out_size, void* d_ws, size_t ws_size,
                              hipStream_t stream) {
    const float* x    = (const float*)d_in[0];
    const float* Wqkv = (const float*)d_in[1];
    const float* bqkv = (const float*)d_in[2];
    const float* Wo   = (const float*)d_in[3];
    const float* bo   = (const float*)d_in[4];
    float* out = (float*)d_out;

    u16* xb    = (u16*)d_ws;          // 4M u16 : x bf16
    u16* wqkvt = xb + 4194304;        // 3M : Wqkv^T
    u16* wot   = wqkvt + 3145728;     // 1M : Wo^T
    u16* qkvb  = wot + 1048576;       // 12M : qkv [b,t,3C] bf16 (Q pre-scaled; V third unused)
    u16* vtb   = qkvb + 12582912;     // 4M : V^T [b,h,d,t] (written by gemm_bt<0>)
    u16* yb    = vtb + 4194304;       // 4M : attn out [b,t,c]

    prep<<<5120, 256, 0, stream>>>(x, xb, Wqkv, wqkvt, Wo, wot);
    gemm_bt<0><<<dim3(32, 24), 256, 0, stream>>>(xb, wqkvt, bqkv, qkvb, vtb,
                                                 nullptr, 4096, 3072, 1024);
    attn<<<dim3(16, 32), 512, 0, stream>>>(qkvb, vtb, yb);
    gemm_bt64<<<dim3(64, 8), 512, 0, stream>>>(yb, wot, bo, out, 4096, 1024, 1024);
}